// Round 7
// baseline (60.968 us; speedup 1.0000x reference)
//
#include <hip/hip_runtime.h>

#define B_    4
#define N_    1024
#define FIN   128
#define FOUT  256
#define NH    8
#define ND    32
#define NSL   0.2f
#define LOG2E 1.44269504088896340736f

typedef _Float16 half8 __attribute__((ext_vector_type(8)));
typedef __fp16 fp16x2 __attribute__((ext_vector_type(2)));
typedef float f32x4 __attribute__((ext_vector_type(4)));

// ---- K0: bit-pack adj (int32 0/1) -> 1 bit/edge. Wave ballot: bit l = lane l. ----
// 4M elems; wave covers 64/iter. adjb32[j>>5] bit (j&31) == adj[i][j] (LE u64 store).
__global__ __launch_bounds__(256) void gat_k0(
    const int* __restrict__ adj, unsigned long long* __restrict__ adjb64)
{
  const int gw = (blockIdx.x * 256 + threadIdx.x) >> 6;   // global wave id, 4096 total
  const int lane = threadIdx.x & 63;
  const size_t base0 = (size_t)gw * 1024;
#pragma unroll
  for (int it = 0; it < 16; ++it) {
    const size_t base = base0 + it * 64;
    const unsigned long long m = __ballot(adj[base + lane] != 0);
    if (lane == 0) adjb64[base >> 6] = m;
  }
}

// ---- K1: g16T[hb][f][n] = f16(h@W); elt/ert[hb][n] = LOG2E*(g.a_l / g.a_r) ----
__global__ __launch_bounds__(256) void gat_k1(
    const float* __restrict__ h, const float* __restrict__ W,
    const float* __restrict__ a_vec, _Float16* __restrict__ g16,
    float* __restrict__ elt, float* __restrict__ ert)
{
  __shared__ float hs[16][FIN];   // 8 KB
  const int t = threadIdx.x;
  const int row0 = blockIdx.x * 16;

  {
    const float4* src = (const float4*)(h + (size_t)row0 * FIN);
    float4* dst = (float4*)&hs[0][0];
    dst[t]       = src[t];
    dst[t + 256] = src[t + 256];
  }
  __syncthreads();

  const int cp = t & 127;
  const int c0 = 2 * cp;
  const int r0 = (t >> 7) * 8;
  float acc0[8] = {0.f,0.f,0.f,0.f,0.f,0.f,0.f,0.f};
  float acc1[8] = {0.f,0.f,0.f,0.f,0.f,0.f,0.f,0.f};

#pragma unroll 4
  for (int k4 = 0; k4 < FIN; k4 += 4) {
    const float2 w0 = *(const float2*)&W[(k4 + 0) * FOUT + c0];
    const float2 w1 = *(const float2*)&W[(k4 + 1) * FOUT + c0];
    const float2 w2 = *(const float2*)&W[(k4 + 2) * FOUT + c0];
    const float2 w3 = *(const float2*)&W[(k4 + 3) * FOUT + c0];
#pragma unroll
    for (int r = 0; r < 8; ++r) {
      const float4 hv = *(const float4*)&hs[r0 + r][k4];
      acc0[r] += hv.x * w0.x + hv.y * w1.x + hv.z * w2.x + hv.w * w3.x;
      acc1[r] += hv.x * w0.y + hv.y * w1.y + hv.z * w2.y + hv.w * w3.y;
    }
  }

  const int f0 = c0 & 31, head = c0 >> 5;
  const int b = row0 >> 10, n0 = row0 & 1023;
  const int hb = b * NH + head;

  half8 hv0, hv1;
#pragma unroll
  for (int r = 0; r < 8; ++r) { hv0[r] = (_Float16)acc0[r]; hv1[r] = (_Float16)acc1[r]; }
  *(half8*)&g16[((size_t)hb * ND + f0) * N_ + n0 + r0]     = hv0;
  *(half8*)&g16[((size_t)hb * ND + f0 + 1) * N_ + n0 + r0] = hv1;

  const float al0 = a_vec[f0] * LOG2E,      al1 = a_vec[f0 + 1] * LOG2E;
  const float ar0 = a_vec[ND + f0] * LOG2E, ar1 = a_vec[ND + f0 + 1] * LOG2E;
#pragma unroll
  for (int r = 0; r < 8; ++r) {
    float pl = acc0[r] * al0 + acc1[r] * al1;
    float pr = acc0[r] * ar0 + acc1[r] * ar1;
#pragma unroll
    for (int m = 8; m >= 1; m >>= 1) {
      pl += __shfl_xor(pl, m, 16);
      pr += __shfl_xor(pr, m, 16);
    }
    if ((t & 15) == 0) {
      elt[(size_t)hb * N_ + n0 + r0 + r] = pl;
      ert[(size_t)hb * N_ + n0 + r0 + r] = pr;
    }
  }
}

// one 32-j sub-chunk x4: P-gen from bitmask + 3 MFMA, all operands in registers
#define COMPUTE4(G0v, G1v, AW, KB)                                              \
  _Pragma("unroll")                                                             \
  for (int u = 0; u < 4; ++u) {                                                 \
    const unsigned word = ((const unsigned*)&(AW))[u];                          \
    const unsigned wsh = word >> (kg * 8);                                      \
    const int ks = wv * 256 + (KB) + u * 32 + kg * 8;                           \
    const float4 e0 = *(const float4*)&er_s[ks];                                \
    const float4 e1 = *(const float4*)&er_s[ks + 4];                            \
    const float er8[8] = {e0.x, e0.y, e0.z, e0.w, e1.x, e1.y, e1.z, e1.w};      \
    float pv[8];                                                                \
    _Pragma("unroll")                                                           \
    for (int e = 0; e < 8; ++e) {                                               \
      float x = el_i + er8[e];                                                  \
      x = fmaxf(x, NSL * x);                                                    \
      float p;                                                                  \
      asm("v_exp_f32 %0, %1" : "=v"(p) : "v"(x));                               \
      pv[e] = ((wsh >> e) & 1u) ? p : 0.f;                                      \
    }                                                                           \
    union { half8 h8; unsigned uu[4]; } P;                                      \
    _Pragma("unroll")                                                           \
    for (int q = 0; q < 4; ++q) {                                               \
      union { fp16x2 hh; unsigned uu; } cv;                                     \
      cv.hh = __builtin_amdgcn_cvt_pkrtz(pv[2 * q], pv[2 * q + 1]);             \
      P.uu[q] = cv.uu;                                                          \
    }                                                                           \
    acc0 = __builtin_amdgcn_mfma_f32_16x16x32_f16(G0v[u], P.h8, acc0, 0, 0, 0); \
    acc1 = __builtin_amdgcn_mfma_f32_16x16x32_f16(G1v[u], P.h8, acc1, 0, 0, 0); \
    accd = __builtin_amdgcn_mfma_f32_16x16x32_f16(ones, P.h8, accd, 0, 0, 0);   \
  }

// ---- K3: bitmask adj (2 int4/wave) + XCD swizzle (all i-tiles of one (b,head)
// on one XCD -> g16 panel served from its private L2). dpart epilogue unchanged.
__global__ __launch_bounds__(256, 3) void gat_k3(
    const unsigned* __restrict__ adjb, const _Float16* __restrict__ g16,
    const float* __restrict__ elt, const float* __restrict__ ert,
    float* __restrict__ out)
{
  __shared__ float er_s[N_];
  __shared__ float dpart[4][32][17];
  __shared__ float denp[4][16];

  const int t = threadIdx.x;
  const int u0 = blockIdx.x;
  const int v  = ((u0 & 7) << 8) | (u0 >> 3);   // XCD swizzle (2048 = 8*256, bijective)
  const int it   = v & 63;
  const int head = (v >> 6) & 7;
  const int b    = v >> 9;
  const int i0   = it * 16;
  const int hb   = b * NH + head;

  *(float4*)&er_s[4 * t] = *(const float4*)&ert[(size_t)hb * N_ + 4 * t];
  __syncthreads();

  const int wv = t >> 6, lane = t & 63;
  const int li = lane & 15, kg = lane >> 4;

  const float el_i = elt[(size_t)hb * N_ + i0 + li];
  const int4* __restrict__ abase =
      (const int4*)(adjb + ((size_t)(b * N_ + i0 + li)) * 32 + wv * 8);
  const _Float16* __restrict__ arow0 =
      g16 + ((size_t)hb * ND + li) * N_ + wv * 256 + kg * 8;
  const _Float16* __restrict__ arow1 = arow0 + (size_t)16 * N_;

  f32x4 acc0 = {0.f, 0.f, 0.f, 0.f};
  f32x4 acc1 = {0.f, 0.f, 0.f, 0.f};
  f32x4 accd = {0.f, 0.f, 0.f, 0.f};
  const half8 ones = {(_Float16)1.f, (_Float16)1.f, (_Float16)1.f, (_Float16)1.f,
                      (_Float16)1.f, (_Float16)1.f, (_Float16)1.f, (_Float16)1.f};

  // prefetch everything: 2 int4 (adj bits, 512 j) + 16 half8 (g16)
  const int4 AWa = abase[0];           // words for j-chunks u=0..3 (this wave's slice)
  const int4 AWb = abase[1];           // u=4..7
  half8 Ga0[4], Ga1[4], Gb0[4], Gb1[4];
#pragma unroll
  for (int uq = 0; uq < 4; ++uq) {
    Ga0[uq] = *(const half8*)(arow0 + uq * 32);
    Ga1[uq] = *(const half8*)(arow1 + uq * 32);
    Gb0[uq] = *(const half8*)(arow0 + 128 + uq * 32);
    Gb1[uq] = *(const half8*)(arow1 + 128 + uq * 32);
  }

  COMPUTE4(Ga0, Ga1, AWa, 0)
  COMPUTE4(Gb0, Gb1, AWb, 128)

#pragma unroll
  for (int r = 0; r < 4; ++r) {
    dpart[wv][4 * kg + r][li]      = acc0[r];
    dpart[wv][16 + 4 * kg + r][li] = acc1[r];
  }
  if (lane < 16) denp[wv][lane] = accd[0];
  __syncthreads();

  for (int o = t; o < 512; o += 256) {
    const int f = o & 31, ii = o >> 5;
    const float s  = dpart[0][f][ii] + dpart[1][f][ii]
                   + dpart[2][f][ii] + dpart[3][f][ii];
    const float dn = denp[0][ii] + denp[1][ii] + denp[2][ii] + denp[3][ii];
    float w = s / dn;
    w = fmaxf(w, NSL * w);
    out[((size_t)(b * N_ + i0 + ii)) * FOUT + head * ND + f] = w;
  }
}

extern "C" void kernel_launch(void* const* d_in, const int* in_sizes, int n_in,
                              void* d_out, int out_size, void* d_ws, size_t ws_size,
                              hipStream_t stream) {
  const float* h     = (const float*)d_in[0];
  const int*   adj   = (const int*)d_in[1];
  const float* W     = (const float*)d_in[2];
  const float* a_vec = (const float*)d_in[3];
  float* out = (float*)d_out;

  _Float16* g16 = (_Float16*)d_ws;                          // 2 MB
  float* elt = (float*)(g16 + (size_t)B_ * NH * ND * N_);   // 128 KB
  float* ert = elt + (size_t)B_ * NH * N_;                  // 128 KB
  unsigned long long* adjb64 = (unsigned long long*)(ert + (size_t)B_ * NH * N_);  // 512 KB

  gat_k0<<<1024, 256, 0, stream>>>(adj, adjb64);
  gat_k1<<<(B_ * N_) / 16, 256, 0, stream>>>(h, W, a_vec, g16, elt, ert);
  gat_k3<<<B_ * NH * (N_ / 16), 256, 0, stream>>>((const unsigned*)adjb64, g16, elt, ert, out);
  // duplicate k3 launch (idempotent): round-8 drops it; dur delta == exact k3 cost
  gat_k3<<<B_ * NH * (N_ / 16), 256, 0, stream>>>((const unsigned*)adjb64, g16, elt, ert, out);
}